// Round 18
// baseline (6485.302 us; speedup 1.0000x reference)
//
#include <hip/hip_runtime.h>

// ---------- types ----------
typedef float  f32x4  __attribute__((ext_vector_type(4)));
typedef short  short8 __attribute__((ext_vector_type(8)));
typedef __bf16 bf16x8 __attribute__((ext_vector_type(8)));

#define B_SZ 2048
#define T_SZ 120
#define H_SZ 256
#define G3   768      // 3H
#define A_SZ 40

#define MFMA_BF16 __builtin_amdgcn_mfma_f32_16x16x32_bf16

union U8 { short8 s; bf16x8 b; };
__device__ __forceinline__ bf16x8 as_bf(short8 s){ U8 u; u.s = s; return u.b; }

__device__ __forceinline__ unsigned short f2bf(float x){
  unsigned u = __float_as_uint(x);
  return (unsigned short)((u + 0x7FFFu + ((u >> 16) & 1u)) >> 16);
}
__device__ __forceinline__ float bf2f(unsigned short h){
  return __uint_as_float(((unsigned)h) << 16);
}
__device__ __forceinline__ void cvt_hilo(float x, short& hi, short& lo){
  unsigned short h = f2bf(x);
  hi = (short)h;
  lo = (short)f2bf(x - bf2f(h));
}
__device__ __forceinline__ float sigm(float x){ return 1.0f / (1.0f + __expf(-x)); }
__device__ __forceinline__ float tanh_(float x){
  float a = fabsf(x);
  float t = 1.0f - 2.0f / (__expf(2.0f * a) + 1.0f);
  return copysignf(t, x);
}

// ---------- zero-init scratch state ----------
__global__ void zinit(float* __restrict__ p, size_t n){
  size_t i = (size_t)blockIdx.x * 256 + threadIdx.x;
  size_t stride = (size_t)gridDim.x * 256;
  for (; i < n; i += stride) p[i] = 0.0f;
}

// ---------- single packing kernel: all 6 weight brick sets + WvT bricks ----------
__global__ void packall(const float* __restrict__ WihC, const float* __restrict__ WhhC,
                        const float* __restrict__ WihA, const float* __restrict__ WhhA,
                        const float* __restrict__ WihI, const float* __restrict__ WhhI,
                        const float* __restrict__ Wv,
                        short* __restrict__ pIhC, short* __restrict__ pHhC,
                        short* __restrict__ pIhA, short* __restrict__ pHhA,
                        short* __restrict__ pIhI, short* __restrict__ pHhI,
                        short* __restrict__ pWvT)
{
  int b = blockIdx.x;
  int lane = threadIdx.x;
  const float* src; short* dst; int K;
  if      (b < 192)  { src = WihC; dst = pIhC; K = 128; }
  else if (b < 576)  { b -= 192;  src = WhhC; dst = pHhC; K = 256; }
  else if (b < 720)  { b -= 576;  src = WihA; dst = pIhA; K = 96;  }
  else if (b < 1104) { b -= 720;  src = WhhA; dst = pHhA; K = 256; }
  else if (b < 1872) { b -= 1104; src = WihI; dst = pIhI; K = 512; }
  else if (b < 2256) { b -= 1872; src = WhhI; dst = pHhI; K = 256; }
  else {
    int bb = b - 2256;
    int q = bb >> 3, kt = bb & 7;
    int a = q * 16 + (lane & 15);
    int k = kt * 32 + (lane >> 4) * 8;
    size_t o = (((size_t)q * 8 + kt) * 64 + lane) * 8;
#pragma unroll
    for (int i = 0; i < 8; i++){
      float v = (a < A_SZ) ? Wv[(size_t)a * H_SZ + k + i] : 0.0f;
      pWvT[o + i] = (short)f2bf(v);
    }
    return;
  }
  int KT = K >> 5;
  int nt = b / KT, kt = b % KT;
  const float* s = src + (size_t)(nt * 16 + (lane & 15)) * K + kt * 32 + (lane >> 4) * 8;
  size_t o = (((size_t)nt * KT + kt) * 64 + lane) * 8;
#pragma unroll
  for (int i = 0; i < 8; i++) dst[o + i] = (short)f2bf(s[i]);
}

// ---------- leaf GRU body: 32 rows/WG (2 A-frags share each W brick) ----------
template<int D, int KI>
__device__ __forceinline__ void leaf32_body(
    const float* __restrict__ x, const short* __restrict__ Wih,
    const short* __restrict__ Whh, const float* __restrict__ bih,
    const float* __restrict__ bhh, short* __restrict__ outp, int ooff,
    float* __restrict__ hs, int b0, int t0, int tcnt,
    short* hhi, short* hlo, short* xhi)
{
  constexpr int XP  = D + 8;
  constexpr int NST = 4 * D;          // 32 rows * D/8 chunks
  constexpr int CPR = D / 8;
  int tid = threadIdx.x, w = tid >> 6, lane = tid & 63;
  int arow = lane & 15, kgrp = lane >> 4;
  int c0 = w * 16 + arow;
  int msk = (arow & 7) << 4;

  float bir[2], biz[2], bin_[2], bhn[2];
#pragma unroll
  for (int j = 0; j < 2; j++){
    int c = c0 + j * 128;
    bir[j] = bih[c] + bhh[c];
    biz[j] = bih[256 + c] + bhh[256 + c];
    bin_[j] = bih[512 + c];
    bhn[j] = bhh[512 + c];
  }

  int srow = tid / CPR, scol = (tid % CPR) * 8;
  bool stg = tid < NST;
  const float* sx = x + ((size_t)(b0 + srow) * T_SZ + t0) * D + scol;
  short* xwh = xhi + srow * XP + scol;

  // out-store mapping: 32 rows x 16 thread-chunks of 16 shorts (2 short8 each)
  int orow = tid >> 4, ocb = (tid & 15) * 16;
  const char* ord0 = (const char*)hhi + orow * 512 + ((ocb * 2) ^ ((orow & 7) << 4));
  const char* ord1 = (const char*)hhi + orow * 512 + (((ocb + 8) * 2) ^ ((orow & 7) << 4));
  short* owp = outp + (size_t)(b0 + orow) * tcnt * 512 + ooff + ocb;

  float hreg[2][2][4];
#pragma unroll
  for (int f = 0; f < 2; f++)
#pragma unroll
  for (int j = 0; j < 2; j++)
#pragma unroll
  for (int i = 0; i < 4; i++){
    int row = f * 16 + kgrp * 4 + i, c = c0 + j * 128;
    float v = hs[(size_t)(b0 + row) * H_SZ + c];
    hreg[f][j][i] = v;
    short h_, l_; cvt_hilo(v, h_, l_);
    int off = row * 512 + ((c * 2) ^ ((row & 7) << 4));
    *(short*)((char*)hhi + off) = h_;
    *(short*)((char*)hlo + off) = l_;
  }
  if (stg){
    f32x4 a0 = *(const f32x4*)sx;
    f32x4 a1 = *(const f32x4*)(sx + 4);
    short8 h8;
#pragma unroll
    for (int i = 0; i < 4; i++){ h8[i] = (short)f2bf(a0[i]); h8[4+i] = (short)f2bf(a1[i]); }
    *(short8*)xwh = h8;
  }
  __syncthreads();

  const char *hhp[2], *hlp[2], *xhp[2];
#pragma unroll
  for (int f = 0; f < 2; f++){
    hhp[f] = (const char*)hhi + (f * 16 + arow) * 512;
    hlp[f] = (const char*)hlo + (f * 16 + arow) * 512;
    xhp[f] = (const char*)xhi + ((f * 16 + arow) * XP + kgrp * 8) * 2;
  }

  const f32x4 zero = {0.f, 0.f, 0.f, 0.f};
  for (int t = 0; t < tcnt; t++){
    if (t > 0){
      *(short8*)(owp + (size_t)(t - 1) * 512) = *(const short8*)ord0;
      *(short8*)(owp + (size_t)(t - 1) * 512 + 8) = *(const short8*)ord1;
    }

    f32x4 acc[2][6], accNi[2][2];
#pragma unroll
    for (int f = 0; f < 2; f++){
#pragma unroll
      for (int q = 0; q < 6; q++) acc[f][q] = zero;
      accNi[f][0] = zero; accNi[f][1] = zero;
    }

    // ---- ih phase ----
#pragma unroll
    for (int kt = 0; kt < KI; kt++){
      short8 wb[6];
#pragma unroll
      for (int q = 0; q < 6; q++)
        wb[q] = *(const short8*)(Wih + (((w + 8 * q) * KI + kt) * 64 + lane) * 8);
      bf16x8 ah[2];
#pragma unroll
      for (int f = 0; f < 2; f++)
        ah[f] = as_bf(*(const short8*)(xhp[f] + kt * 64));
#pragma unroll
      for (int q = 0; q < 6; q++){
        bf16x8 bw = as_bf(wb[q]);
#pragma unroll
        for (int f = 0; f < 2; f++){
          if (q < 4) acc[f][q] = MFMA_BF16(ah[f], bw, acc[f][q], 0, 0, 0);
          else       accNi[f][q-4] = MFMA_BF16(ah[f], bw, accNi[f][q-4], 0, 0, 0);
        }
      }
    }
    // ---- hh phase: each W brick feeds 2 frags x (hi,lo) = 4 MFMAs ----
#pragma unroll
    for (int kt = 0; kt < 8; kt++){
      short8 wb[6];
#pragma unroll
      for (int q = 0; q < 6; q++)
        wb[q] = *(const short8*)(Whh + (((w + 8 * q) * 8 + kt) * 64 + lane) * 8);
      int kb = (kt * 64 + kgrp * 16) ^ msk;
      bf16x8 ah[2], al[2];
#pragma unroll
      for (int f = 0; f < 2; f++){
        ah[f] = as_bf(*(const short8*)(hhp[f] + kb));
        al[f] = as_bf(*(const short8*)(hlp[f] + kb));
      }
#pragma unroll
      for (int q = 0; q < 6; q++){
        bf16x8 bw = as_bf(wb[q]);
#pragma unroll
        for (int f = 0; f < 2; f++){
          acc[f][q] = MFMA_BF16(ah[f], bw, acc[f][q], 0, 0, 0);
          acc[f][q] = MFMA_BF16(al[f], bw, acc[f][q], 0, 0, 0);
        }
      }
    }
    __syncthreads();   // b1

    f32x4 a0, a1;
    bool ds = stg && (t + 1 < tcnt);
    if (ds){
      a0 = *(const f32x4*)(sx + (size_t)(t + 1) * D);
      a1 = *(const f32x4*)(sx + (size_t)(t + 1) * D + 4);
    }

#pragma unroll
    for (int f = 0; f < 2; f++)
#pragma unroll
    for (int j = 0; j < 2; j++)
#pragma unroll
    for (int i = 0; i < 4; i++){
      float rr = sigm(acc[f][j][i] + bir[j]);
      float zz = sigm(acc[f][2 + j][i] + biz[j]);
      float nn = tanh_(accNi[f][j][i] + bin_[j] + rr * (acc[f][4 + j][i] + bhn[j]));
      float hv = (1.0f - zz) * nn + zz * hreg[f][j][i];
      hreg[f][j][i] = hv;
      int row = f * 16 + kgrp * 4 + i, c = c0 + j * 128;
      short h_, l_; cvt_hilo(hv, h_, l_);
      int off = row * 512 + ((c * 2) ^ ((row & 7) << 4));
      *(short*)((char*)hhi + off) = h_;
      *(short*)((char*)hlo + off) = l_;
    }
    if (ds){
      short8 h8;
#pragma unroll
      for (int i = 0; i < 4; i++){ h8[i] = (short)f2bf(a0[i]); h8[4+i] = (short)f2bf(a1[i]); }
      *(short8*)xwh = h8;
    }
    __syncthreads();   // b2
  }

  *(short8*)(owp + (size_t)(tcnt - 1) * 512) = *(const short8*)ord0;
  *(short8*)(owp + (size_t)(tcnt - 1) * 512 + 8) = *(const short8*)ord1;

#pragma unroll
  for (int f = 0; f < 2; f++)
#pragma unroll
  for (int j = 0; j < 2; j++)
#pragma unroll
  for (int i = 0; i < 4; i++){
    int row = f * 16 + kgrp * 4 + i;
    hs[(size_t)(b0 + row) * H_SZ + c0 + j * 128] = hreg[f][j][i];
  }
}

// ---------- fully-fused inter: ih (OcaH@WihI via MFMA, x staged in LDS) +
//            hh + attention. 16 rows/WG. Gi buffer eliminated. ----------
__device__ __forceinline__ void interf_body(
    int bid, const short* __restrict__ xh,   // OcaH chunk [B, tcnt, 512] bf16
    const short* __restrict__ Wih, const short* __restrict__ Whh,
    const float* __restrict__ bih, const float* __restrict__ bhh,
    const short* __restrict__ WvT,
    const float* __restrict__ bv, const float* __restrict__ wu,
    float* __restrict__ ctx, float* __restrict__ lsum,
    float* __restrict__ hs, int tcnt,
    short* hhi, short* hlo, short* xq, short* wvl, float* esh)
{
  int b0 = bid * 16;
  int tid = threadIdx.x, w = tid >> 6, lane = tid & 63;
  int arow = lane & 15, kgrp = lane >> 4;
  int c0 = w * 16 + arow;
  int msk = (arow & 7) << 4;

  float bir[2], biz[2], bin_[2], bhn[2];
#pragma unroll
  for (int j = 0; j < 2; j++){
    int c = c0 + j * 128;
    bir[j] = bih[c] + bhh[c];
    biz[j] = bih[256 + c] + bhh[256 + c];
    bin_[j] = bih[512 + c];
    bhn[j] = bhh[512 + c];
  }

  float wuv[3], bvv[3];
#pragma unroll
  for (int q = 0; q < 3; q++){
    int a = q * 16 + arow;
    wuv[q] = (a < A_SZ) ? wu[a] : 0.0f;
    bvv[q] = (a < A_SZ) ? bv[a] : 0.0f;
  }

  for (int i = tid; i < 3 * 8 * 64; i += 512)
    *(short8*)(wvl + i * 8) = *(const short8*)(WvT + (size_t)i * 8);

  // x staging: 16 rows x 32 chunks of 16 shorts = 512 threads
  int srow = tid >> 5, scol = (tid & 31) * 16;
  const short* sx = xh + (size_t)(b0 + srow) * tcnt * 512 + scol;
  short* xw = xq + srow * 520 + scol;

  float hreg[2][4];
#pragma unroll
  for (int j = 0; j < 2; j++)
#pragma unroll
  for (int i = 0; i < 4; i++){
    int row = kgrp * 4 + i, c = c0 + j * 128;
    float v = hs[(size_t)(b0 + row) * H_SZ + c];
    hreg[j][i] = v;
    short h_, l_; cvt_hilo(v, h_, l_);
    int off = row * 512 + ((c * 2) ^ ((row & 7) << 4));
    *(short*)((char*)hhi + off) = h_;
    *(short*)((char*)hlo + off) = l_;
  }
  // stage x(t=0)
  *(short8*)xw = *(const short8*)sx;
  *(short8*)(xw + 8) = *(const short8*)(sx + 8);
  __syncthreads();

  const char* hhp = (const char*)hhi + arow * 512;
  const char* hlp = (const char*)hlo + arow * 512;
  const short* xqp = xq + arow * 520 + kgrp * 8;

  float ctxa[2][4] = {{0.f,0.f,0.f,0.f},{0.f,0.f,0.f,0.f}};
  float lsr[4] = {0.f, 0.f, 0.f, 0.f};

  const f32x4 zero = {0.f, 0.f, 0.f, 0.f};
  for (int t = 0; t < tcnt; t++){
    f32x4 acc[6], accNi[2];
#pragma unroll
    for (int q = 0; q < 6; q++) acc[q] = zero;
    accNi[0] = zero; accNi[1] = zero;

    // ---- ih phase: x from LDS (bf16, 1-pass), KI=16 ----
#pragma unroll
    for (int kt = 0; kt < 16; kt++){
      short8 wb[6];
#pragma unroll
      for (int q = 0; q < 6; q++)
        wb[q] = *(const short8*)(Wih + (((w + 8 * q) * 16 + kt) * 64 + lane) * 8);
      bf16x8 ah = as_bf(*(const short8*)(xqp + kt * 32));
#pragma unroll
      for (int q = 0; q < 6; q++){
        bf16x8 bw = as_bf(wb[q]);
        if (q < 4) acc[q] = MFMA_BF16(ah, bw, acc[q], 0, 0, 0);
        else       accNi[q-4] = MFMA_BF16(ah, bw, accNi[q-4], 0, 0, 0);
      }
    }
    // ---- hh phase: h hi/lo from LDS, 2-pass ----
#pragma unroll
    for (int kt = 0; kt < 8; kt++){
      short8 wb[6];
#pragma unroll
      for (int q = 0; q < 6; q++)
        wb[q] = *(const short8*)(Whh + (((w + 8 * q) * 8 + kt) * 64 + lane) * 8);
      int kb = (kt * 64 + kgrp * 16) ^ msk;
      bf16x8 ah = as_bf(*(const short8*)(hhp + kb));
      bf16x8 al = as_bf(*(const short8*)(hlp + kb));
#pragma unroll
      for (int q = 0; q < 6; q++){
        bf16x8 bw = as_bf(wb[q]);
        acc[q] = MFMA_BF16(ah, bw, acc[q], 0, 0, 0);
        acc[q] = MFMA_BF16(al, bw, acc[q], 0, 0, 0);
      }
    }

    // wave 0: attention scores for out-row t-1 (state in hhi)
    if (w == 0 && t > 0){
      f32x4 um[3];
#pragma unroll
      for (int q = 0; q < 3; q++) um[q] = zero;
#pragma unroll
      for (int kt = 0; kt < 8; kt++){
        int kb = (kt * 64 + kgrp * 16) ^ msk;
        bf16x8 ah = as_bf(*(const short8*)(hhp + kb));
#pragma unroll
        for (int q = 0; q < 3; q++){
          bf16x8 bw = as_bf(*(const short8*)(wvl + ((q * 8 + kt) * 64 + lane) * 8));
          um[q] = MFMA_BF16(ah, bw, um[q], 0, 0, 0);
        }
      }
      f32x4 sp;
#pragma unroll
      for (int i = 0; i < 4; i++){
        float v = 0.f;
#pragma unroll
        for (int q = 0; q < 3; q++)
          v += wuv[q] * tanh_(um[q][i] + bvv[q]);
        sp[i] = v;
      }
#pragma unroll
      for (int d = 1; d < 16; d <<= 1){
#pragma unroll
        for (int i = 0; i < 4; i++)
          sp[i] += __shfl_xor(sp[i], d);
      }
      if (arow == 0){
#pragma unroll
        for (int i = 0; i < 4; i++){
          float e = __expf(sp[i]);
          esh[kgrp * 4 + i] = e;
          lsr[i] += e;
        }
      }
    }
    __syncthreads();   // b1 (publishes esh; all LDS reads done)

    if (t > 0){
#pragma unroll
      for (int i = 0; i < 4; i++){
        float e = esh[kgrp * 4 + i];
#pragma unroll
        for (int j = 0; j < 2; j++)
          ctxa[j][i] += e * hreg[j][i];
      }
    }

    // issue x(t+1) loads (hide under gates)
    short8 a0s, a1s;
    bool ds = (t + 1 < tcnt);
    if (ds){
      a0s = *(const short8*)(sx + (size_t)(t + 1) * 512);
      a1s = *(const short8*)(sx + (size_t)(t + 1) * 512 + 8);
    }

#pragma unroll
    for (int j = 0; j < 2; j++)
#pragma unroll
    for (int i = 0; i < 4; i++){
      float rr = sigm(acc[j][i] + bir[j]);
      float zz = sigm(acc[2 + j][i] + biz[j]);
      float nn = tanh_(accNi[j][i] + bin_[j] + rr * (acc[4 + j][i] + bhn[j]));
      float hv = (1.0f - zz) * nn + zz * hreg[j][i];
      hreg[j][i] = hv;
      int row = kgrp * 4 + i, c = c0 + j * 128;
      short h_, l_; cvt_hilo(hv, h_, l_);
      int off = row * 512 + ((c * 2) ^ ((row & 7) << 4));
      *(short*)((char*)hhi + off) = h_;
      *(short*)((char*)hlo + off) = l_;
    }
    if (ds){
      *(short8*)xw = a0s;
      *(short8*)(xw + 8) = a1s;
    }
    __syncthreads();   // b2
  }

  // epilogue: last row's scores + ctx
  if (w == 0){
    f32x4 um[3];
#pragma unroll
    for (int q = 0; q < 3; q++) um[q] = zero;
#pragma unroll
    for (int kt = 0; kt < 8; kt++){
      int kb = (kt * 64 + kgrp * 16) ^ msk;
      bf16x8 ah = as_bf(*(const short8*)(hhp + kb));
#pragma unroll
      for (int q = 0; q < 3; q++){
        bf16x8 bw = as_bf(*(const short8*)(wvl + ((q * 8 + kt) * 64 + lane) * 8));
        um[q] = MFMA_BF16(ah, bw, um[q], 0, 0, 0);
      }
    }
    f32x4 sp;
#pragma unroll
    for (int i = 0; i < 4; i++){
      float v = 0.f;
#pragma unroll
      for (int q = 0; q < 3; q++)
        v += wuv[q] * tanh_(um[q][i] + bvv[q]);
      sp[i] = v;
    }
#pragma unroll
    for (int d = 1; d < 16; d <<= 1){
#pragma unroll
      for (int i = 0; i < 4; i++)
        sp[i] += __shfl_xor(sp[i], d);
    }
    if (arow == 0){
#pragma unroll
      for (int i = 0; i < 4; i++){
        float e = __expf(sp[i]);
        esh[kgrp * 4 + i] = e;
        lsr[i] += e;
      }
    }
  }
  __syncthreads();
#pragma unroll
  for (int i = 0; i < 4; i++){
    float e = esh[kgrp * 4 + i];
#pragma unroll
    for (int j = 0; j < 2; j++)
      ctxa[j][i] += e * hreg[j][i];
  }

#pragma unroll
  for (int j = 0; j < 2; j++)
#pragma unroll
  for (int i = 0; i < 4; i++){
    int row = kgrp * 4 + i;
    hs[(size_t)(b0 + row) * H_SZ + c0 + j * 128] = hreg[j][i];
    ctx[(size_t)(b0 + row) * H_SZ + c0 + j * 128] += ctxa[j][i];
  }
  if (w == 0 && arow == 0){
#pragma unroll
    for (int i = 0; i < 4; i++)
      lsum[b0 + kgrp * 4 + i] += lsr[i];
  }
}

// ---------- fused 2-stage pipeline: interf(k-1) | leaf32(k) ----------
__global__ __launch_bounds__(512, 2) void fused2(
    int nIb,
    // interf (chunk k-1)
    const short* __restrict__ xhI, const short* __restrict__ WihI_,
    const short* __restrict__ WhhI_, const float* __restrict__ bihI_,
    const float* __restrict__ bhhI_, const short* __restrict__ WvT,
    const float* __restrict__ bv, const float* __restrict__ wu,
    float* __restrict__ ctx, float* __restrict__ lsum,
    float* __restrict__ hsI, int tcntI,
    // leaf (chunk k)
    const float* __restrict__ x0, const short* __restrict__ WihL0,
    const short* __restrict__ WhhL0, const float* __restrict__ bihL0,
    const float* __restrict__ bhhL0,
    const float* __restrict__ x1, const short* __restrict__ WihL1,
    const short* __restrict__ WhhL1, const float* __restrict__ bihL1,
    const float* __restrict__ bhhL1,
    short* __restrict__ outL, float* __restrict__ hsC, float* __restrict__ hsA,
    int t0L, int tcntL)
{
  __shared__ short smem[28864];   // 57.73 KB -> 2 blocks/CU
  int bid = blockIdx.x;
  if (bid < nIb){
    // hhi 4096 | hlo 4096 | xq 16*520=8320 | wvl 12288 | esh 32
    interf_body(bid, xhI, WihI_, WhhI_, bihI_, bhhI_, WvT, bv, wu,
                ctx, lsum, hsI, tcntI,
                smem, smem + 4096, smem + 8192, smem + 16512,
                (float*)(smem + 28800));
  } else {
    int lb = bid - nIb;
    short* hhi = smem;                 // 32*256 = 8192 shorts
    short* hlo = smem + 8192;
    short* xhi = smem + 16384;         // 32*136 = 4352 shorts
    if (lb < 64)
      leaf32_body<128, 4>(x0, WihL0, WhhL0, bihL0, bhhL0, outL, 0, hsC,
                          lb * 32, t0L, tcntL, hhi, hlo, xhi);
    else
      leaf32_body<96, 3>(x1, WihL1, WhhL1, bihL1, bhhL1, outL, 256, hsA,
                         (lb - 64) * 32, t0L, tcntL, hhi, hlo, xhi);
  }
}

__global__ __launch_bounds__(256, 1) void attn_fin(
    const float* __restrict__ ctx, const float* __restrict__ lsum,
    float* __restrict__ out)
{
  int b = blockIdx.x, tid = threadIdx.x;
  out[(size_t)b * H_SZ + tid] = ctx[(size_t)b * H_SZ + tid] / lsum[b];
}

// ---------- host ----------
extern "C" void kernel_launch(void* const* d_in, const int* in_sizes, int n_in,
                              void* d_out, int out_size, void* d_ws, size_t ws_size,
                              hipStream_t stream)
{
  (void)in_sizes; (void)n_in; (void)out_size;
  const float* crime = (const float*)d_in[0];
  const float* anom  = (const float*)d_in[1];
  const float* WihC = (const float*)d_in[2];
  const float* WhhC = (const float*)d_in[3];
  const float* bihC = (const float*)d_in[4];
  const float* bhhC = (const float*)d_in[5];
  const float* WihA = (const float*)d_in[6];
  const float* WhhA = (const float*)d_in[7];
  const float* bihA = (const float*)d_in[8];
  const float* bhhA = (const float*)d_in[9];
  const float* WihI = (const float*)d_in[10];
  const float* WhhI = (const float*)d_in[11];
  const float* bihI = (const float*)d_in[12];
  const float* bhhI = (const float*)d_in[13];
  const float* Wv = (const float*)d_in[14];
  const float* bv = (const float*)d_in[15];
  const float* wu = (const float*)d_in[16];
  float* out = (float*)d_out;

  char* ws = (char*)d_ws;
  size_t off = 0;
  auto take = [&](size_t n){ size_t r = off; off += (n + 255) & ~(size_t)255; return r; };

  short* pIhC = (short*)(ws + take((size_t)G3 * 128 * 2));
  short* pHhC = (short*)(ws + take((size_t)G3 * 256 * 2));
  short* pIhA = (short*)(ws + take((size_t)G3 * 96 * 2));
  short* pHhA = (short*)(ws + take((size_t)G3 * 256 * 2));
  short* pIhI = (short*)(ws + take((size_t)G3 * 512 * 2));
  short* pHhI = (short*)(ws + take((size_t)G3 * 256 * 2));
  short* pWvT = (short*)(ws + take((size_t)3 * 8 * 64 * 8 * 2));

  size_t state_off = off;
  float* hsC  = (float*)(ws + take((size_t)B_SZ * H_SZ * 4));
  float* hsA  = (float*)(ws + take((size_t)B_SZ * H_SZ * 4));
  float* hsI  = (float*)(ws + take((size_t)B_SZ * H_SZ * 4));
  float* ctx  = (float*)(ws + take((size_t)B_SZ * H_SZ * 4));
  float* lsum = (float*)(ws + take((size_t)B_SZ * 4));
  size_t state_end = off;

  // double-buffered chunk scratch: 2x OcaH bf16 (512 shorts) per step
  size_t per2 = (size_t)B_SZ * (512 * 2) * 2;   // 4.19 MB per timestep
  size_t avail = (ws_size > off + 8192) ? (ws_size - off - 8192) : 0;
  int TC = (int)(avail / per2);
  if (TC > 12) TC = 12;
  if (TC < 1) TC = 1;
  if (TC > T_SZ) TC = T_SZ;
  int nc = (T_SZ + TC - 1) / TC;

  short* OcaH[2];
  OcaH[0] = (short*)(ws + take((size_t)B_SZ * TC * 512 * 2));
  OcaH[1] = (short*)(ws + take((size_t)B_SZ * TC * 512 * 2));

  auto tcn = [&](int j){
    if (j < 0 || j >= nc) return 0;
    int r = T_SZ - j * TC;
    return r < TC ? r : TC;
  };

  // zero h-states, ctx, lsum (every launch: deterministic)
  zinit<<<2048, 256, 0, stream>>>((float*)(ws + state_off), (state_end - state_off) / 4);
  packall<<<2280, 64, 0, stream>>>(WihC, WhhC, WihA, WhhA, WihI, WhhI, Wv,
                                   pIhC, pHhC, pIhA, pHhA, pIhI, pHhI, pWvT);

  // 2-stage software pipeline over chunks: interf(k-1) | leaf32(k)
  for (int k = 0; k <= nc; k++){
    int tL = tcn(k), tI = tcn(k - 1);
    int nLb = tL ? 128 : 0;
    int nIb = tI ? 128 : 0;
    int grid = nIb + nLb;
    if (grid == 0) continue;
    fused2<<<grid, 512, 0, stream>>>(
        nIb,
        OcaH[(k - 1) & 1], pIhI, pHhI, bihI, bhhI, pWvT, bv, wu,
        ctx, lsum, hsI, tI,
        crime, pIhC, pHhC, bihC, bhhC,
        anom,  pIhA, pHhA, bihA, bhhA,
        OcaH[k & 1], hsC, hsA, k * TC, tL);
  }
  attn_fin<<<B_SZ, 256, 0, stream>>>(ctx, lsum, out);
}

// Round 19
// 3172.445 us; speedup vs baseline: 2.0443x; 2.0443x over previous
//
#include <hip/hip_runtime.h>

// ---------- types ----------
typedef float  f32x4  __attribute__((ext_vector_type(4)));
typedef short  short8 __attribute__((ext_vector_type(8)));
typedef __bf16 bf16x8 __attribute__((ext_vector_type(8)));

#define B_SZ 2048
#define T_SZ 120
#define H_SZ 256
#define G3   768      // 3H
#define A_SZ 40

#define MFMA_BF16 __builtin_amdgcn_mfma_f32_16x16x32_bf16

union U8 { short8 s; bf16x8 b; };
__device__ __forceinline__ bf16x8 as_bf(short8 s){ U8 u; u.s = s; return u.b; }

__device__ __forceinline__ unsigned short f2bf(float x){
  unsigned u = __float_as_uint(x);
  return (unsigned short)((u + 0x7FFFu + ((u >> 16) & 1u)) >> 16);
}
__device__ __forceinline__ float bf2f(unsigned short h){
  return __uint_as_float(((unsigned)h) << 16);
}
__device__ __forceinline__ void cvt_hilo(float x, short& hi, short& lo){
  unsigned short h = f2bf(x);
  hi = (short)h;
  lo = (short)f2bf(x - bf2f(h));
}
__device__ __forceinline__ float sigm(float x){ return 1.0f / (1.0f + __expf(-x)); }
__device__ __forceinline__ float tanh_(float x){
  float a = fabsf(x);
  float t = 1.0f - 2.0f / (__expf(2.0f * a) + 1.0f);
  return copysignf(t, x);
}

// ---------- zero-init scratch state ----------
__global__ void zinit(float* __restrict__ p, size_t n){
  size_t i = (size_t)blockIdx.x * 256 + threadIdx.x;
  size_t stride = (size_t)gridDim.x * 256;
  for (; i < n; i += stride) p[i] = 0.0f;
}

// ---------- single packing kernel: all 6 weight brick sets + WvT bricks ----------
__global__ void packall(const float* __restrict__ WihC, const float* __restrict__ WhhC,
                        const float* __restrict__ WihA, const float* __restrict__ WhhA,
                        const float* __restrict__ WihI, const float* __restrict__ WhhI,
                        const float* __restrict__ Wv,
                        short* __restrict__ pIhC, short* __restrict__ pHhC,
                        short* __restrict__ pIhA, short* __restrict__ pHhA,
                        short* __restrict__ pIhI, short* __restrict__ pHhI,
                        short* __restrict__ pWvT)
{
  int b = blockIdx.x;
  int lane = threadIdx.x;
  const float* src; short* dst; int K;
  if      (b < 192)  { src = WihC; dst = pIhC; K = 128; }
  else if (b < 576)  { b -= 192;  src = WhhC; dst = pHhC; K = 256; }
  else if (b < 720)  { b -= 576;  src = WihA; dst = pIhA; K = 96;  }
  else if (b < 1104) { b -= 720;  src = WhhA; dst = pHhA; K = 256; }
  else if (b < 1872) { b -= 1104; src = WihI; dst = pIhI; K = 512; }
  else if (b < 2256) { b -= 1872; src = WhhI; dst = pHhI; K = 256; }
  else {
    int bb = b - 2256;
    int q = bb >> 3, kt = bb & 7;
    int a = q * 16 + (lane & 15);
    int k = kt * 32 + (lane >> 4) * 8;
    size_t o = (((size_t)q * 8 + kt) * 64 + lane) * 8;
#pragma unroll
    for (int i = 0; i < 8; i++){
      float v = (a < A_SZ) ? Wv[(size_t)a * H_SZ + k + i] : 0.0f;
      pWvT[o + i] = (short)f2bf(v);
    }
    return;
  }
  int KT = K >> 5;
  int nt = b / KT, kt = b % KT;
  const float* s = src + (size_t)(nt * 16 + (lane & 15)) * K + kt * 32 + (lane >> 4) * 8;
  size_t o = (((size_t)nt * KT + kt) * 64 + lane) * 8;
#pragma unroll
  for (int i = 0; i < 8; i++) dst[o + i] = (short)f2bf(s[i]);
}

// ---------- gemm body: 64-row tile, 1-pass bf16, A staged in LDS ----------
__device__ __forceinline__ void gemm_body(
    int bid, const short* __restrict__ A, const short* __restrict__ Bhi,
    const float* __restrict__ b1, const float* __restrict__ b2,
    float* __restrict__ C, short* Ash)   // Ash: 64*520 shorts
{
  int tid = threadIdx.x;
  int w = tid >> 6, lane = tid & 63;
  int mg = w & 1, ng = w >> 1;
  int m0 = bid * 64;
  int nb = ng * 12;
  const int KT = 16;

  {
    int r = tid >> 3, s0 = (tid & 7) * 64;
    const short* src = A + (size_t)(m0 + r) * 512 + s0;
    short* dst = Ash + r * 520 + s0;
#pragma unroll
    for (int i = 0; i < 8; i++)
      *(short8*)(dst + i * 8) = *(const short8*)(src + i * 8);
  }
  __syncthreads();

  const f32x4 zero = {0.f, 0.f, 0.f, 0.f};
  f32x4 acc[2][12];
#pragma unroll
  for (int f = 0; f < 2; f++)
#pragma unroll
    for (int q = 0; q < 12; q++) acc[f][q] = zero;

  int rr = lane & 15, ks = lane >> 4;
  const short* Ap[2];
#pragma unroll
  for (int f = 0; f < 2; f++)
    Ap[f] = Ash + (mg * 32 + f * 16 + rr) * 520 + ks * 8;

  for (int kt = 0; kt < KT; ++kt){
    bf16x8 ahb[2];
#pragma unroll
    for (int f = 0; f < 2; f++)
      ahb[f] = as_bf(*(const short8*)(Ap[f] + kt * 32));
#pragma unroll
    for (int q = 0; q < 12; q++){
      int bo = (((nb + q) * KT + kt) * 64 + lane) * 8;
      bf16x8 bh = as_bf(*(const short8*)(Bhi + bo));
#pragma unroll
      for (int f = 0; f < 2; f++)
        acc[f][q] = MFMA_BF16(ahb[f], bh, acc[f][q], 0, 0, 0);
    }
  }
  int nc = lane & 15;
  int rb = lane >> 4;
#pragma unroll
  for (int q = 0; q < 12; q++){
    int n = (nb + q) * 16 + nc;
    float bias = b1[n] + (n < 512 ? b2[n] : 0.0f);
#pragma unroll
    for (int f = 0; f < 2; f++)
#pragma unroll
      for (int i = 0; i < 4; i++)
        C[(size_t)(m0 + mg * 32 + f * 16 + rb * 4 + i) * G3 + n] = acc[f][q][i] + bias;
  }
}

// ---------- leaf GRU body: 32 rows/WG (2 A-frags share each W brick) ----------
template<int D, int KI>
__device__ __forceinline__ void leaf32_body(
    const float* __restrict__ x, const short* __restrict__ Wih,
    const short* __restrict__ Whh, const float* __restrict__ bih,
    const float* __restrict__ bhh, short* __restrict__ outp, int ooff,
    float* __restrict__ hs, int b0, int t0, int tcnt,
    short* hhi, short* hlo, short* xhi)
{
  constexpr int XP  = D + 8;
  constexpr int NST = 4 * D;          // 32 rows * D/8 chunks
  constexpr int CPR = D / 8;
  int tid = threadIdx.x, w = tid >> 6, lane = tid & 63;
  int arow = lane & 15, kgrp = lane >> 4;
  int c0 = w * 16 + arow;
  int msk = (arow & 7) << 4;

  float bir[2], biz[2], bin_[2], bhn[2];
#pragma unroll
  for (int j = 0; j < 2; j++){
    int c = c0 + j * 128;
    bir[j] = bih[c] + bhh[c];
    biz[j] = bih[256 + c] + bhh[256 + c];
    bin_[j] = bih[512 + c];
    bhn[j] = bhh[512 + c];
  }

  int srow = tid / CPR, scol = (tid % CPR) * 8;
  bool stg = tid < NST;
  const float* sx = x + ((size_t)(b0 + srow) * T_SZ + t0) * D + scol;
  short* xwh = xhi + srow * XP + scol;

  // out-store mapping: 32 rows x 16 thread-chunks of 16 shorts (2 short8 each)
  int orow = tid >> 4, ocb = (tid & 15) * 16;
  const char* ord0 = (const char*)hhi + orow * 512 + ((ocb * 2) ^ ((orow & 7) << 4));
  const char* ord1 = (const char*)hhi + orow * 512 + (((ocb + 8) * 2) ^ ((orow & 7) << 4));
  short* owp = outp + (size_t)(b0 + orow) * tcnt * 512 + ooff + ocb;

  float hreg[2][2][4];
#pragma unroll
  for (int f = 0; f < 2; f++)
#pragma unroll
  for (int j = 0; j < 2; j++)
#pragma unroll
  for (int i = 0; i < 4; i++){
    int row = f * 16 + kgrp * 4 + i, c = c0 + j * 128;
    float v = hs[(size_t)(b0 + row) * H_SZ + c];
    hreg[f][j][i] = v;
    short h_, l_; cvt_hilo(v, h_, l_);
    int off = row * 512 + ((c * 2) ^ ((row & 7) << 4));
    *(short*)((char*)hhi + off) = h_;
    *(short*)((char*)hlo + off) = l_;
  }
  if (stg){
    f32x4 a0 = *(const f32x4*)sx;
    f32x4 a1 = *(const f32x4*)(sx + 4);
    short8 h8;
#pragma unroll
    for (int i = 0; i < 4; i++){ h8[i] = (short)f2bf(a0[i]); h8[4+i] = (short)f2bf(a1[i]); }
    *(short8*)xwh = h8;
  }
  __syncthreads();

  const char *hhp[2], *hlp[2], *xhp[2];
#pragma unroll
  for (int f = 0; f < 2; f++){
    hhp[f] = (const char*)hhi + (f * 16 + arow) * 512;
    hlp[f] = (const char*)hlo + (f * 16 + arow) * 512;
    xhp[f] = (const char*)xhi + ((f * 16 + arow) * XP + kgrp * 8) * 2;
  }

  const f32x4 zero = {0.f, 0.f, 0.f, 0.f};
  for (int t = 0; t < tcnt; t++){
    if (t > 0){
      *(short8*)(owp + (size_t)(t - 1) * 512) = *(const short8*)ord0;
      *(short8*)(owp + (size_t)(t - 1) * 512 + 8) = *(const short8*)ord1;
    }

    f32x4 acc[2][6], accNi[2][2];
#pragma unroll
    for (int f = 0; f < 2; f++){
#pragma unroll
      for (int q = 0; q < 6; q++) acc[f][q] = zero;
      accNi[f][0] = zero; accNi[f][1] = zero;
    }

    // ---- ih phase ----
#pragma unroll
    for (int kt = 0; kt < KI; kt++){
      short8 wb[6];
#pragma unroll
      for (int q = 0; q < 6; q++)
        wb[q] = *(const short8*)(Wih + (((w + 8 * q) * KI + kt) * 64 + lane) * 8);
      bf16x8 ah[2];
#pragma unroll
      for (int f = 0; f < 2; f++)
        ah[f] = as_bf(*(const short8*)(xhp[f] + kt * 64));
#pragma unroll
      for (int q = 0; q < 6; q++){
        bf16x8 bw = as_bf(wb[q]);
#pragma unroll
        for (int f = 0; f < 2; f++){
          if (q < 4) acc[f][q] = MFMA_BF16(ah[f], bw, acc[f][q], 0, 0, 0);
          else       accNi[f][q-4] = MFMA_BF16(ah[f], bw, accNi[f][q-4], 0, 0, 0);
        }
      }
    }
    // ---- hh phase: each W brick feeds 2 frags x (hi,lo) = 4 MFMAs ----
#pragma unroll
    for (int kt = 0; kt < 8; kt++){
      short8 wb[6];
#pragma unroll
      for (int q = 0; q < 6; q++)
        wb[q] = *(const short8*)(Whh + (((w + 8 * q) * 8 + kt) * 64 + lane) * 8);
      int kb = (kt * 64 + kgrp * 16) ^ msk;
      bf16x8 ah[2], al[2];
#pragma unroll
      for (int f = 0; f < 2; f++){
        ah[f] = as_bf(*(const short8*)(hhp[f] + kb));
        al[f] = as_bf(*(const short8*)(hlp[f] + kb));
      }
#pragma unroll
      for (int q = 0; q < 6; q++){
        bf16x8 bw = as_bf(wb[q]);
#pragma unroll
        for (int f = 0; f < 2; f++){
          acc[f][q] = MFMA_BF16(ah[f], bw, acc[f][q], 0, 0, 0);
          acc[f][q] = MFMA_BF16(al[f], bw, acc[f][q], 0, 0, 0);
        }
      }
    }
    __syncthreads();   // b1

    f32x4 a0, a1;
    bool ds = stg && (t + 1 < tcnt);
    if (ds){
      a0 = *(const f32x4*)(sx + (size_t)(t + 1) * D);
      a1 = *(const f32x4*)(sx + (size_t)(t + 1) * D + 4);
    }

#pragma unroll
    for (int f = 0; f < 2; f++)
#pragma unroll
    for (int j = 0; j < 2; j++)
#pragma unroll
    for (int i = 0; i < 4; i++){
      float rr = sigm(acc[f][j][i] + bir[j]);
      float zz = sigm(acc[f][2 + j][i] + biz[j]);
      float nn = tanh_(accNi[f][j][i] + bin_[j] + rr * (acc[f][4 + j][i] + bhn[j]));
      float hv = (1.0f - zz) * nn + zz * hreg[f][j][i];
      hreg[f][j][i] = hv;
      int row = f * 16 + kgrp * 4 + i, c = c0 + j * 128;
      short h_, l_; cvt_hilo(hv, h_, l_);
      int off = row * 512 + ((c * 2) ^ ((row & 7) << 4));
      *(short*)((char*)hhi + off) = h_;
      *(short*)((char*)hlo + off) = l_;
    }
    if (ds){
      short8 h8;
#pragma unroll
      for (int i = 0; i < 4; i++){ h8[i] = (short)f2bf(a0[i]); h8[4+i] = (short)f2bf(a1[i]); }
      *(short8*)xwh = h8;
    }
    __syncthreads();   // b2
  }

  *(short8*)(owp + (size_t)(tcnt - 1) * 512) = *(const short8*)ord0;
  *(short8*)(owp + (size_t)(tcnt - 1) * 512 + 8) = *(const short8*)ord1;

#pragma unroll
  for (int f = 0; f < 2; f++)
#pragma unroll
  for (int j = 0; j < 2; j++)
#pragma unroll
  for (int i = 0; i < 4; i++){
    int row = f * 16 + kgrp * 4 + i;
    hs[(size_t)(b0 + row) * H_SZ + c0 + j * 128] = hreg[f][j][i];
  }
}

// ---------- inter GRU + fused attention body: 16 rows/WG ----------
__device__ __forceinline__ void inter_body(
    int bid, const float* __restrict__ gi,
    const short* __restrict__ Whh, const float* __restrict__ bhh,
    const short* __restrict__ WvT,
    const float* __restrict__ bv, const float* __restrict__ wu,
    float* __restrict__ ctx, float* __restrict__ lsum,
    float* __restrict__ hs, int tcnt,
    short* hhi, short* hlo, short* wvl, float* esh)
{
  int b0 = bid * 16;
  int tid = threadIdx.x, w = tid >> 6, lane = tid & 63;
  int arow = lane & 15, kgrp = lane >> 4;
  int c0 = w * 16 + arow;
  int msk = (arow & 7) << 4;

  float bhn[2];
  bhn[0] = bhh[512 + c0];
  bhn[1] = bhh[512 + c0 + 128];

  float wuv[3], bvv[3];
#pragma unroll
  for (int q = 0; q < 3; q++){
    int a = q * 16 + arow;
    wuv[q] = (a < A_SZ) ? wu[a] : 0.0f;
    bvv[q] = (a < A_SZ) ? bv[a] : 0.0f;
  }

  for (int i = tid; i < 3 * 8 * 64; i += 512)
    *(short8*)(wvl + i * 8) = *(const short8*)(WvT + (size_t)i * 8);

  float hreg[2][4];
#pragma unroll
  for (int j = 0; j < 2; j++)
#pragma unroll
  for (int i = 0; i < 4; i++){
    int row = kgrp * 4 + i, c = c0 + j * 128;
    float v = hs[(size_t)(b0 + row) * H_SZ + c];
    hreg[j][i] = v;
    short h_, l_; cvt_hilo(v, h_, l_);
    int off = row * 512 + ((c * 2) ^ ((row & 7) << 4));
    *(short*)((char*)hhi + off) = h_;
    *(short*)((char*)hlo + off) = l_;
  }
  __syncthreads();

  const char* hhp = (const char*)hhi + arow * 512;
  const char* hlp = (const char*)hlo + arow * 512;
  const float* gp[4];
#pragma unroll
  for (int i = 0; i < 4; i++)
    gp[i] = gi + (size_t)(b0 + kgrp * 4 + i) * tcnt * G3;

  float ctxa[2][4] = {{0.f,0.f,0.f,0.f},{0.f,0.f,0.f,0.f}};
  float lsr[4] = {0.f, 0.f, 0.f, 0.f};

  const f32x4 zero = {0.f, 0.f, 0.f, 0.f};
  for (int t = 0; t < tcnt; t++){
    float gvr[2][4], gvz[2][4], gvn[2][4];
#pragma unroll
    for (int j = 0; j < 2; j++)
#pragma unroll
    for (int i = 0; i < 4; i++){
      const float* g = gp[i] + (size_t)t * G3 + c0 + j * 128;
      gvr[j][i] = g[0];
      gvz[j][i] = g[256];
      gvn[j][i] = g[512];
    }

    f32x4 acc[6];
#pragma unroll
    for (int q = 0; q < 6; q++) acc[q] = zero;

    short8 wb[6], wn[6];
#pragma unroll
    for (int q = 0; q < 6; q++)
      wb[q] = *(const short8*)(Whh + (((w + 8 * q) * 8) * 64 + lane) * 8);
#pragma unroll
    for (int kt = 0; kt < 8; kt++){
      if (kt < 7){
#pragma unroll
        for (int q = 0; q < 6; q++)
          wn[q] = *(const short8*)(Whh + (((w + 8 * q) * 8 + kt + 1) * 64 + lane) * 8);
      }
      int kb = (kt * 64 + kgrp * 16) ^ msk;
      bf16x8 ah = as_bf(*(const short8*)(hhp + kb));
      bf16x8 al = as_bf(*(const short8*)(hlp + kb));
#pragma unroll
      for (int q = 0; q < 6; q++){
        bf16x8 bw = as_bf(wb[q]);
        acc[q] = MFMA_BF16(ah, bw, acc[q], 0, 0, 0);
        acc[q] = MFMA_BF16(al, bw, acc[q], 0, 0, 0);
      }
      if (kt < 7){
#pragma unroll
        for (int q = 0; q < 6; q++) wb[q] = wn[q];
      }
    }

    // wave 0: scores for out-row t-1 (state in hhi)
    if (w == 0 && t > 0){
      f32x4 um[3];
#pragma unroll
      for (int q = 0; q < 3; q++) um[q] = zero;
#pragma unroll
      for (int kt = 0; kt < 8; kt++){
        int kb = (kt * 64 + kgrp * 16) ^ msk;
        bf16x8 ah = as_bf(*(const short8*)(hhp + kb));
#pragma unroll
        for (int q = 0; q < 3; q++){
          bf16x8 bw = as_bf(*(const short8*)(wvl + ((q * 8 + kt) * 64 + lane) * 8));
          um[q] = MFMA_BF16(ah, bw, um[q], 0, 0, 0);
        }
      }
      f32x4 sp;
#pragma unroll
      for (int i = 0; i < 4; i++){
        float v = 0.f;
#pragma unroll
        for (int q = 0; q < 3; q++)
          v += wuv[q] * tanh_(um[q][i] + bvv[q]);
        sp[i] = v;
      }
#pragma unroll
      for (int d = 1; d < 16; d <<= 1){
#pragma unroll
        for (int i = 0; i < 4; i++)
          sp[i] += __shfl_xor(sp[i], d);
      }
      if (arow == 0){
#pragma unroll
        for (int i = 0; i < 4; i++){
          float e = __expf(sp[i]);
          esh[kgrp * 4 + i] = e;
          lsr[i] += e;
        }
      }
    }
    __syncthreads();   // b1 (publishes esh)

    if (t > 0){
#pragma unroll
      for (int i = 0; i < 4; i++){
        float e = esh[kgrp * 4 + i];
#pragma unroll
        for (int j = 0; j < 2; j++)
          ctxa[j][i] += e * hreg[j][i];
      }
    }

#pragma unroll
    for (int j = 0; j < 2; j++)
#pragma unroll
    for (int i = 0; i < 4; i++){
      float rr = sigm(gvr[j][i] + acc[j][i]);
      float zz = sigm(gvz[j][i] + acc[2 + j][i]);
      float nn = tanh_(gvn[j][i] + rr * (acc[4 + j][i] + bhn[j]));
      float hv = (1.0f - zz) * nn + zz * hreg[j][i];
      hreg[j][i] = hv;
      int row = kgrp * 4 + i, c = c0 + j * 128;
      short h_, l_; cvt_hilo(hv, h_, l_);
      int off = row * 512 + ((c * 2) ^ ((row & 7) << 4));
      *(short*)((char*)hhi + off) = h_;
      *(short*)((char*)hlo + off) = l_;
    }
    __syncthreads();   // b2
  }

  // epilogue: last row's scores + ctx
  if (w == 0){
    f32x4 um[3];
#pragma unroll
    for (int q = 0; q < 3; q++) um[q] = zero;
#pragma unroll
    for (int kt = 0; kt < 8; kt++){
      int kb = (kt * 64 + kgrp * 16) ^ msk;
      bf16x8 ah = as_bf(*(const short8*)(hhp + kb));
#pragma unroll
      for (int q = 0; q < 3; q++){
        bf16x8 bw = as_bf(*(const short8*)(wvl + ((q * 8 + kt) * 64 + lane) * 8));
        um[q] = MFMA_BF16(ah, bw, um[q], 0, 0, 0);
      }
    }
    f32x4 sp;
#pragma unroll
    for (int i = 0; i < 4; i++){
      float v = 0.f;
#pragma unroll
      for (int q = 0; q < 3; q++)
        v += wuv[q] * tanh_(um[q][i] + bvv[q]);
      sp[i] = v;
    }
#pragma unroll
    for (int d = 1; d < 16; d <<= 1){
#pragma unroll
      for (int i = 0; i < 4; i++)
        sp[i] += __shfl_xor(sp[i], d);
    }
    if (arow == 0){
#pragma unroll
      for (int i = 0; i < 4; i++){
        float e = __expf(sp[i]);
        esh[kgrp * 4 + i] = e;
        lsr[i] += e;
      }
    }
  }
  __syncthreads();
#pragma unroll
  for (int i = 0; i < 4; i++){
    float e = esh[kgrp * 4 + i];
#pragma unroll
    for (int j = 0; j < 2; j++)
      ctxa[j][i] += e * hreg[j][i];
  }

#pragma unroll
  for (int j = 0; j < 2; j++)
#pragma unroll
  for (int i = 0; i < 4; i++){
    int row = kgrp * 4 + i;
    hs[(size_t)(b0 + row) * H_SZ + c0 + j * 128] = hreg[j][i];
    ctx[(size_t)(b0 + row) * H_SZ + c0 + j * 128] += ctxa[j][i];
  }
  if (w == 0 && arow == 0){
#pragma unroll
    for (int i = 0; i < 4; i++)
      lsum[b0 + kgrp * 4 + i] += lsr[i];
  }
}

// ---------- fused 3-stage pipeline: inter(k-2) | leaf32(k) | gemm(k-1) ----------
__global__ __launch_bounds__(512, 2) void fused3(
    int nIb, int nLb,
    // inter (chunk k-2)
    const float* __restrict__ giI, const short* __restrict__ WhhI_,
    const float* __restrict__ bhhI_, const short* __restrict__ WvT,
    const float* __restrict__ bv, const float* __restrict__ wu,
    float* __restrict__ ctx, float* __restrict__ lsum,
    float* __restrict__ hsI, int tcntI,
    // leaf (chunk k)
    const float* __restrict__ x0, const short* __restrict__ WihL0,
    const short* __restrict__ WhhL0, const float* __restrict__ bihL0,
    const float* __restrict__ bhhL0,
    const float* __restrict__ x1, const short* __restrict__ WihL1,
    const short* __restrict__ WhhL1, const float* __restrict__ bihL1,
    const float* __restrict__ bhhL1,
    short* __restrict__ outL, float* __restrict__ hsC, float* __restrict__ hsA,
    int t0L, int tcntL,
    // gemm (chunk k-1)
    const short* __restrict__ Ag, const short* __restrict__ BhiG,
    const float* __restrict__ b1G, const float* __restrict__ b2G,
    float* __restrict__ Cg)
{
  __shared__ short smem[64 * 520];   // 66.56 KB
  int bid = blockIdx.x;
  if (bid < nIb){
    // hhi 4096 | hlo 4096 | wvl 12288 | esh
    inter_body(bid, giI, WhhI_, bhhI_, WvT, bv, wu, ctx, lsum, hsI, tcntI,
               smem, smem + 4096, smem + 8192, (float*)(smem + 20480));
  } else if (bid < nIb + nLb){
    int lb = bid - nIb;
    short* hhi = smem;                 // 32*256 = 8192 shorts
    short* hlo = smem + 8192;
    short* xhi = smem + 16384;         // 32*136 = 4352 shorts
    if (lb < 64)
      leaf32_body<128, 4>(x0, WihL0, WhhL0, bihL0, bhhL0, outL, 0, hsC,
                          lb * 32, t0L, tcntL, hhi, hlo, xhi);
    else
      leaf32_body<96, 3>(x1, WihL1, WhhL1, bihL1, bhhL1, outL, 256, hsA,
                         (lb - 64) * 32, t0L, tcntL, hhi, hlo, xhi);
  } else {
    gemm_body(bid - nIb - nLb, Ag, BhiG, b1G, b2G, Cg, smem);
  }
}

__global__ __launch_bounds__(256, 1) void attn_fin(
    const float* __restrict__ ctx, const float* __restrict__ lsum,
    float* __restrict__ out)
{
  int b = blockIdx.x, tid = threadIdx.x;
  out[(size_t)b * H_SZ + tid] = ctx[(size_t)b * H_SZ + tid] / lsum[b];
}

// ---------- host ----------
extern "C" void kernel_launch(void* const* d_in, const int* in_sizes, int n_in,
                              void* d_out, int out_size, void* d_ws, size_t ws_size,
                              hipStream_t stream)
{
  (void)in_sizes; (void)n_in; (void)out_size;
  const float* crime = (const float*)d_in[0];
  const float* anom  = (const float*)d_in[1];
  const float* WihC = (const float*)d_in[2];
  const float* WhhC = (const float*)d_in[3];
  const float* bihC = (const float*)d_in[4];
  const float* bhhC = (const float*)d_in[5];
  const float* WihA = (const float*)d_in[6];
  const float* WhhA = (const float*)d_in[7];
  const float* bihA = (const float*)d_in[8];
  const float* bhhA = (const float*)d_in[9];
  const float* WihI = (const float*)d_in[10];
  const float* WhhI = (const float*)d_in[11];
  const float* bihI = (const float*)d_in[12];
  const float* bhhI = (const float*)d_in[13];
  const float* Wv = (const float*)d_in[14];
  const float* bv = (const float*)d_in[15];
  const float* wu = (const float*)d_in[16];
  float* out = (float*)d_out;

  char* ws = (char*)d_ws;
  size_t off = 0;
  auto take = [&](size_t n){ size_t r = off; off += (n + 255) & ~(size_t)255; return r; };

  short* pIhC = (short*)(ws + take((size_t)G3 * 128 * 2));
  short* pHhC = (short*)(ws + take((size_t)G3 * 256 * 2));
  short* pIhA = (short*)(ws + take((size_t)G3 * 96 * 2));
  short* pHhA = (short*)(ws + take((size_t)G3 * 256 * 2));
  short* pIhI = (short*)(ws + take((size_t)G3 * 512 * 2));
  short* pHhI = (short*)(ws + take((size_t)G3 * 256 * 2));
  short* pWvT = (short*)(ws + take((size_t)3 * 8 * 64 * 8 * 2));

  size_t state_off = off;
  float* hsC  = (float*)(ws + take((size_t)B_SZ * H_SZ * 4));
  float* hsA  = (float*)(ws + take((size_t)B_SZ * H_SZ * 4));
  float* hsI  = (float*)(ws + take((size_t)B_SZ * H_SZ * 4));
  float* ctx  = (float*)(ws + take((size_t)B_SZ * H_SZ * 4));
  float* lsum = (float*)(ws + take((size_t)B_SZ * 4));
  size_t state_end = off;

  // double-buffered chunk scratch: 2x (Gi fp32 768 + OcaH bf16 512) per step
  size_t per2 = (size_t)B_SZ * (G3 * 4 + 512 * 2) * 2;   // 16.78 MB per timestep
  size_t avail = (ws_size > off + 8192) ? (ws_size - off - 8192) : 0;
  int TC = (int)(avail / per2);
  if (TC > 12) TC = 12;
  if (TC < 1) TC = 1;
  if (TC > T_SZ) TC = T_SZ;
  int nc = (T_SZ + TC - 1) / TC;

  float* Gi[2];  short* OcaH[2];
  Gi[0]   = (float*)(ws + take((size_t)B_SZ * TC * G3 * 4));
  Gi[1]   = (float*)(ws + take((size_t)B_SZ * TC * G3 * 4));
  OcaH[0] = (short*)(ws + take((size_t)B_SZ * TC * 512 * 2));
  OcaH[1] = (short*)(ws + take((size_t)B_SZ * TC * 512 * 2));

  auto tcn = [&](int j){
    if (j < 0 || j >= nc) return 0;
    int r = T_SZ - j * TC;
    return r < TC ? r : TC;
  };

  // zero h-states, ctx, lsum (every launch: deterministic)
  zinit<<<2048, 256, 0, stream>>>((float*)(ws + state_off), (state_end - state_off) / 4);
  packall<<<2280, 64, 0, stream>>>(WihC, WhhC, WihA, WhhA, WihI, WhhI, Wv,
                                   pIhC, pHhC, pIhA, pHhA, pIhI, pHhI, pWvT);

  // 3-stage software pipeline over chunks: inter | leaf32 | gemm per launch
  for (int k = 0; k <= nc + 1; k++){
    int tL = tcn(k), tG = tcn(k - 1), tI = tcn(k - 2);
    int nLb = tL ? 128 : 0;
    int nGb = tG ? (B_SZ * tG) / 64 : 0;
    int nIb = tI ? 128 : 0;
    int grid = nIb + nLb + nGb;
    if (grid == 0) continue;
    fused3<<<grid, 512, 0, stream>>>(
        nIb, nLb,
        Gi[k & 1], pHhI, bhhI, pWvT, bv, wu, ctx, lsum, hsI, tI,
        crime, pIhC, pHhC, bihC, bhhC,
        anom,  pIhA, pHhA, bihA, bhhA,
        OcaH[k & 1], hsC, hsA, k * TC, tL,
        OcaH[(k - 1) & 1], pIhI, bihI, bhhI, Gi[(k - 1) & 1]);
  }
  attn_fin<<<B_SZ, 256, 0, stream>>>(ctx, lsum, out);
}

// Round 20
// 3067.010 us; speedup vs baseline: 2.1145x; 1.0344x over previous
//
#include <hip/hip_runtime.h>

// ---------- types ----------
typedef float  f32x4  __attribute__((ext_vector_type(4)));
typedef short  short8 __attribute__((ext_vector_type(8)));
typedef __bf16 bf16x8 __attribute__((ext_vector_type(8)));

#define B_SZ 2048
#define T_SZ 120
#define H_SZ 256
#define G3   768      // 3H
#define A_SZ 40

#define MFMA_BF16 __builtin_amdgcn_mfma_f32_16x16x32_bf16

union U8 { short8 s; bf16x8 b; };
__device__ __forceinline__ bf16x8 as_bf(short8 s){ U8 u; u.s = s; return u.b; }

__device__ __forceinline__ unsigned short f2bf(float x){
  unsigned u = __float_as_uint(x);
  return (unsigned short)((u + 0x7FFFu + ((u >> 16) & 1u)) >> 16);
}
__device__ __forceinline__ float bf2f(unsigned short h){
  return __uint_as_float(((unsigned)h) << 16);
}
__device__ __forceinline__ void cvt_hilo(float x, short& hi, short& lo){
  unsigned short h = f2bf(x);
  hi = (short)h;
  lo = (short)f2bf(x - bf2f(h));
}
__device__ __forceinline__ float sigm(float x){ return 1.0f / (1.0f + __expf(-x)); }
__device__ __forceinline__ float tanh_(float x){
  float a = fabsf(x);
  float t = 1.0f - 2.0f / (__expf(2.0f * a) + 1.0f);
  return copysignf(t, x);
}

// ---------- zero-init scratch state ----------
__global__ void zinit(float* __restrict__ p, size_t n){
  size_t i = (size_t)blockIdx.x * 256 + threadIdx.x;
  size_t stride = (size_t)gridDim.x * 256;
  for (; i < n; i += stride) p[i] = 0.0f;
}

// ---------- single packing kernel: all 6 weight brick sets + WvT bricks ----------
__global__ void packall(const float* __restrict__ WihC, const float* __restrict__ WhhC,
                        const float* __restrict__ WihA, const float* __restrict__ WhhA,
                        const float* __restrict__ WihI, const float* __restrict__ WhhI,
                        const float* __restrict__ Wv,
                        short* __restrict__ pIhC, short* __restrict__ pHhC,
                        short* __restrict__ pIhA, short* __restrict__ pHhA,
                        short* __restrict__ pIhI, short* __restrict__ pHhI,
                        short* __restrict__ pWvT)
{
  int b = blockIdx.x;
  int lane = threadIdx.x;
  const float* src; short* dst; int K;
  if      (b < 192)  { src = WihC; dst = pIhC; K = 128; }
  else if (b < 576)  { b -= 192;  src = WhhC; dst = pHhC; K = 256; }
  else if (b < 720)  { b -= 576;  src = WihA; dst = pIhA; K = 96;  }
  else if (b < 1104) { b -= 720;  src = WhhA; dst = pHhA; K = 256; }
  else if (b < 1872) { b -= 1104; src = WihI; dst = pIhI; K = 512; }
  else if (b < 2256) { b -= 1872; src = WhhI; dst = pHhI; K = 256; }
  else {
    int bb = b - 2256;
    int q = bb >> 3, kt = bb & 7;
    int a = q * 16 + (lane & 15);
    int k = kt * 32 + (lane >> 4) * 8;
    size_t o = (((size_t)q * 8 + kt) * 64 + lane) * 8;
#pragma unroll
    for (int i = 0; i < 8; i++){
      float v = (a < A_SZ) ? Wv[(size_t)a * H_SZ + k + i] : 0.0f;
      pWvT[o + i] = (short)f2bf(v);
    }
    return;
  }
  int KT = K >> 5;
  int nt = b / KT, kt = b % KT;
  const float* s = src + (size_t)(nt * 16 + (lane & 15)) * K + kt * 32 + (lane >> 4) * 8;
  size_t o = (((size_t)nt * KT + kt) * 64 + lane) * 8;
#pragma unroll
  for (int i = 0; i < 8; i++) dst[o + i] = (short)f2bf(s[i]);
}

// ---------- gemm body: 64-row tile, 1-pass bf16, A staged in LDS; C as bf16 ----------
__device__ __forceinline__ void gemm_body(
    int bid, const short* __restrict__ A, const short* __restrict__ Bhi,
    const float* __restrict__ b1, const float* __restrict__ b2,
    short* __restrict__ C, short* Ash)   // Ash: 64*520 shorts
{
  int tid = threadIdx.x;
  int w = tid >> 6, lane = tid & 63;
  int mg = w & 1, ng = w >> 1;
  int m0 = bid * 64;
  int nb = ng * 12;
  const int KT = 16;

  {
    int r = tid >> 3, s0 = (tid & 7) * 64;
    const short* src = A + (size_t)(m0 + r) * 512 + s0;
    short* dst = Ash + r * 520 + s0;
#pragma unroll
    for (int i = 0; i < 8; i++)
      *(short8*)(dst + i * 8) = *(const short8*)(src + i * 8);
  }
  __syncthreads();

  const f32x4 zero = {0.f, 0.f, 0.f, 0.f};
  f32x4 acc[2][12];
#pragma unroll
  for (int f = 0; f < 2; f++)
#pragma unroll
    for (int q = 0; q < 12; q++) acc[f][q] = zero;

  int rr = lane & 15, ks = lane >> 4;
  const short* Ap[2];
#pragma unroll
  for (int f = 0; f < 2; f++)
    Ap[f] = Ash + (mg * 32 + f * 16 + rr) * 520 + ks * 8;

  for (int kt = 0; kt < KT; ++kt){
    bf16x8 ahb[2];
#pragma unroll
    for (int f = 0; f < 2; f++)
      ahb[f] = as_bf(*(const short8*)(Ap[f] + kt * 32));
#pragma unroll
    for (int q = 0; q < 12; q++){
      int bo = (((nb + q) * KT + kt) * 64 + lane) * 8;
      bf16x8 bh = as_bf(*(const short8*)(Bhi + bo));
#pragma unroll
      for (int f = 0; f < 2; f++)
        acc[f][q] = MFMA_BF16(ahb[f], bh, acc[f][q], 0, 0, 0);
    }
  }
  int nc = lane & 15;
  int rb = lane >> 4;
#pragma unroll
  for (int q = 0; q < 12; q++){
    int n = (nb + q) * 16 + nc;
    float bias = b1[n] + (n < 512 ? b2[n] : 0.0f);
#pragma unroll
    for (int f = 0; f < 2; f++)
#pragma unroll
      for (int i = 0; i < 4; i++)
        C[(size_t)(m0 + mg * 32 + f * 16 + rb * 4 + i) * G3 + n] =
            (short)f2bf(acc[f][q][i] + bias);
  }
}

// ---------- leaf GRU body: 32 rows/WG (2 A-frags share each W brick) ----------
template<int D, int KI>
__device__ __forceinline__ void leaf32_body(
    const float* __restrict__ x, const short* __restrict__ Wih,
    const short* __restrict__ Whh, const float* __restrict__ bih,
    const float* __restrict__ bhh, short* __restrict__ outp, int ooff,
    float* __restrict__ hs, int b0, int t0, int tcnt,
    short* hhi, short* hlo, short* xhi)
{
  constexpr int XP  = D + 8;
  constexpr int NST = 4 * D;          // 32 rows * D/8 chunks
  constexpr int CPR = D / 8;
  int tid = threadIdx.x, w = tid >> 6, lane = tid & 63;
  int arow = lane & 15, kgrp = lane >> 4;
  int c0 = w * 16 + arow;
  int msk = (arow & 7) << 4;

  float bir[2], biz[2], bin_[2], bhn[2];
#pragma unroll
  for (int j = 0; j < 2; j++){
    int c = c0 + j * 128;
    bir[j] = bih[c] + bhh[c];
    biz[j] = bih[256 + c] + bhh[256 + c];
    bin_[j] = bih[512 + c];
    bhn[j] = bhh[512 + c];
  }

  int srow = tid / CPR, scol = (tid % CPR) * 8;
  bool stg = tid < NST;
  const float* sx = x + ((size_t)(b0 + srow) * T_SZ + t0) * D + scol;
  short* xwh = xhi + srow * XP + scol;

  // out-store mapping: 32 rows x 16 thread-chunks of 16 shorts (2 short8 each)
  int orow = tid >> 4, ocb = (tid & 15) * 16;
  const char* ord0 = (const char*)hhi + orow * 512 + ((ocb * 2) ^ ((orow & 7) << 4));
  const char* ord1 = (const char*)hhi + orow * 512 + (((ocb + 8) * 2) ^ ((orow & 7) << 4));
  short* owp = outp + (size_t)(b0 + orow) * tcnt * 512 + ooff + ocb;

  float hreg[2][2][4];
#pragma unroll
  for (int f = 0; f < 2; f++)
#pragma unroll
  for (int j = 0; j < 2; j++)
#pragma unroll
  for (int i = 0; i < 4; i++){
    int row = f * 16 + kgrp * 4 + i, c = c0 + j * 128;
    float v = hs[(size_t)(b0 + row) * H_SZ + c];
    hreg[f][j][i] = v;
    short h_, l_; cvt_hilo(v, h_, l_);
    int off = row * 512 + ((c * 2) ^ ((row & 7) << 4));
    *(short*)((char*)hhi + off) = h_;
    *(short*)((char*)hlo + off) = l_;
  }
  if (stg){
    f32x4 a0 = *(const f32x4*)sx;
    f32x4 a1 = *(const f32x4*)(sx + 4);
    short8 h8;
#pragma unroll
    for (int i = 0; i < 4; i++){ h8[i] = (short)f2bf(a0[i]); h8[4+i] = (short)f2bf(a1[i]); }
    *(short8*)xwh = h8;
  }
  __syncthreads();

  const char *hhp[2], *hlp[2], *xhp[2];
#pragma unroll
  for (int f = 0; f < 2; f++){
    hhp[f] = (const char*)hhi + (f * 16 + arow) * 512;
    hlp[f] = (const char*)hlo + (f * 16 + arow) * 512;
    xhp[f] = (const char*)xhi + ((f * 16 + arow) * XP + kgrp * 8) * 2;
  }

  const f32x4 zero = {0.f, 0.f, 0.f, 0.f};
  for (int t = 0; t < tcnt; t++){
    if (t > 0){
      *(short8*)(owp + (size_t)(t - 1) * 512) = *(const short8*)ord0;
      *(short8*)(owp + (size_t)(t - 1) * 512 + 8) = *(const short8*)ord1;
    }

    f32x4 acc[2][6], accNi[2][2];
#pragma unroll
    for (int f = 0; f < 2; f++){
#pragma unroll
      for (int q = 0; q < 6; q++) acc[f][q] = zero;
      accNi[f][0] = zero; accNi[f][1] = zero;
    }

    // ---- ih phase ----
#pragma unroll
    for (int kt = 0; kt < KI; kt++){
      short8 wb[6];
#pragma unroll
      for (int q = 0; q < 6; q++)
        wb[q] = *(const short8*)(Wih + (((w + 8 * q) * KI + kt) * 64 + lane) * 8);
      bf16x8 ah[2];
#pragma unroll
      for (int f = 0; f < 2; f++)
        ah[f] = as_bf(*(const short8*)(xhp[f] + kt * 64));
#pragma unroll
      for (int q = 0; q < 6; q++){
        bf16x8 bw = as_bf(wb[q]);
#pragma unroll
        for (int f = 0; f < 2; f++){
          if (q < 4) acc[f][q] = MFMA_BF16(ah[f], bw, acc[f][q], 0, 0, 0);
          else       accNi[f][q-4] = MFMA_BF16(ah[f], bw, accNi[f][q-4], 0, 0, 0);
        }
      }
    }
    // ---- hh phase: each W brick feeds 2 frags x (hi,lo) = 4 MFMAs ----
#pragma unroll
    for (int kt = 0; kt < 8; kt++){
      short8 wb[6];
#pragma unroll
      for (int q = 0; q < 6; q++)
        wb[q] = *(const short8*)(Whh + (((w + 8 * q) * 8 + kt) * 64 + lane) * 8);
      int kb = (kt * 64 + kgrp * 16) ^ msk;
      bf16x8 ah[2], al[2];
#pragma unroll
      for (int f = 0; f < 2; f++){
        ah[f] = as_bf(*(const short8*)(hhp[f] + kb));
        al[f] = as_bf(*(const short8*)(hlp[f] + kb));
      }
#pragma unroll
      for (int q = 0; q < 6; q++){
        bf16x8 bw = as_bf(wb[q]);
#pragma unroll
        for (int f = 0; f < 2; f++){
          acc[f][q] = MFMA_BF16(ah[f], bw, acc[f][q], 0, 0, 0);
          acc[f][q] = MFMA_BF16(al[f], bw, acc[f][q], 0, 0, 0);
        }
      }
    }
    __syncthreads();   // b1

    f32x4 a0, a1;
    bool ds = stg && (t + 1 < tcnt);
    if (ds){
      a0 = *(const f32x4*)(sx + (size_t)(t + 1) * D);
      a1 = *(const f32x4*)(sx + (size_t)(t + 1) * D + 4);
    }

#pragma unroll
    for (int f = 0; f < 2; f++)
#pragma unroll
    for (int j = 0; j < 2; j++)
#pragma unroll
    for (int i = 0; i < 4; i++){
      float rr = sigm(acc[f][j][i] + bir[j]);
      float zz = sigm(acc[f][2 + j][i] + biz[j]);
      float nn = tanh_(accNi[f][j][i] + bin_[j] + rr * (acc[f][4 + j][i] + bhn[j]));
      float hv = (1.0f - zz) * nn + zz * hreg[f][j][i];
      hreg[f][j][i] = hv;
      int row = f * 16 + kgrp * 4 + i, c = c0 + j * 128;
      short h_, l_; cvt_hilo(hv, h_, l_);
      int off = row * 512 + ((c * 2) ^ ((row & 7) << 4));
      *(short*)((char*)hhi + off) = h_;
      *(short*)((char*)hlo + off) = l_;
    }
    if (ds){
      short8 h8;
#pragma unroll
      for (int i = 0; i < 4; i++){ h8[i] = (short)f2bf(a0[i]); h8[4+i] = (short)f2bf(a1[i]); }
      *(short8*)xwh = h8;
    }
    __syncthreads();   // b2
  }

  *(short8*)(owp + (size_t)(tcnt - 1) * 512) = *(const short8*)ord0;
  *(short8*)(owp + (size_t)(tcnt - 1) * 512 + 8) = *(const short8*)ord1;

#pragma unroll
  for (int f = 0; f < 2; f++)
#pragma unroll
  for (int j = 0; j < 2; j++)
#pragma unroll
  for (int i = 0; i < 4; i++){
    int row = f * 16 + kgrp * 4 + i;
    hs[(size_t)(b0 + row) * H_SZ + c0 + j * 128] = hreg[f][j][i];
  }
}

// ---------- inter GRU + fused attention body: 16 rows/WG, gi in bf16 ----------
__device__ __forceinline__ void inter_body(
    int bid, const short* __restrict__ gi,     // [B*tcnt, 768] bf16
    const short* __restrict__ Whh, const float* __restrict__ bhh,
    const short* __restrict__ WvT,
    const float* __restrict__ bv, const float* __restrict__ wu,
    float* __restrict__ ctx, float* __restrict__ lsum,
    float* __restrict__ hs, int tcnt,
    short* hhi, short* hlo, short* wvl, float* esh)
{
  int b0 = bid * 16;
  int tid = threadIdx.x, w = tid >> 6, lane = tid & 63;
  int arow = lane & 15, kgrp = lane >> 4;
  int c0 = w * 16 + arow;
  int msk = (arow & 7) << 4;

  float bhn[2];
  bhn[0] = bhh[512 + c0];
  bhn[1] = bhh[512 + c0 + 128];

  float wuv[3], bvv[3];
#pragma unroll
  for (int q = 0; q < 3; q++){
    int a = q * 16 + arow;
    wuv[q] = (a < A_SZ) ? wu[a] : 0.0f;
    bvv[q] = (a < A_SZ) ? bv[a] : 0.0f;
  }

  for (int i = tid; i < 3 * 8 * 64; i += 512)
    *(short8*)(wvl + i * 8) = *(const short8*)(WvT + (size_t)i * 8);

  float hreg[2][4];
#pragma unroll
  for (int j = 0; j < 2; j++)
#pragma unroll
  for (int i = 0; i < 4; i++){
    int row = kgrp * 4 + i, c = c0 + j * 128;
    float v = hs[(size_t)(b0 + row) * H_SZ + c];
    hreg[j][i] = v;
    short h_, l_; cvt_hilo(v, h_, l_);
    int off = row * 512 + ((c * 2) ^ ((row & 7) << 4));
    *(short*)((char*)hhi + off) = h_;
    *(short*)((char*)hlo + off) = l_;
  }
  __syncthreads();

  const char* hhp = (const char*)hhi + arow * 512;
  const char* hlp = (const char*)hlo + arow * 512;
  const short* gp[4];
#pragma unroll
  for (int i = 0; i < 4; i++)
    gp[i] = gi + (size_t)(b0 + kgrp * 4 + i) * tcnt * G3;

  float ctxa[2][4] = {{0.f,0.f,0.f,0.f},{0.f,0.f,0.f,0.f}};
  float lsr[4] = {0.f, 0.f, 0.f, 0.f};

  const f32x4 zero = {0.f, 0.f, 0.f, 0.f};
  for (int t = 0; t < tcnt; t++){
    float gvr[2][4], gvz[2][4], gvn[2][4];
#pragma unroll
    for (int j = 0; j < 2; j++)
#pragma unroll
    for (int i = 0; i < 4; i++){
      const short* g = gp[i] + (size_t)t * G3 + c0 + j * 128;
      gvr[j][i] = bf2f((unsigned short)g[0]);
      gvz[j][i] = bf2f((unsigned short)g[256]);
      gvn[j][i] = bf2f((unsigned short)g[512]);
    }

    f32x4 acc[6];
#pragma unroll
    for (int q = 0; q < 6; q++) acc[q] = zero;

    short8 wb[6], wn[6];
#pragma unroll
    for (int q = 0; q < 6; q++)
      wb[q] = *(const short8*)(Whh + (((w + 8 * q) * 8) * 64 + lane) * 8);
#pragma unroll
    for (int kt = 0; kt < 8; kt++){
      if (kt < 7){
#pragma unroll
        for (int q = 0; q < 6; q++)
          wn[q] = *(const short8*)(Whh + (((w + 8 * q) * 8 + kt + 1) * 64 + lane) * 8);
      }
      int kb = (kt * 64 + kgrp * 16) ^ msk;
      bf16x8 ah = as_bf(*(const short8*)(hhp + kb));
      bf16x8 al = as_bf(*(const short8*)(hlp + kb));
#pragma unroll
      for (int q = 0; q < 6; q++){
        bf16x8 bw = as_bf(wb[q]);
        acc[q] = MFMA_BF16(ah, bw, acc[q], 0, 0, 0);
        acc[q] = MFMA_BF16(al, bw, acc[q], 0, 0, 0);
      }
      if (kt < 7){
#pragma unroll
        for (int q = 0; q < 6; q++) wb[q] = wn[q];
      }
    }

    // wave 0: scores for out-row t-1 (state in hhi)
    if (w == 0 && t > 0){
      f32x4 um[3];
#pragma unroll
      for (int q = 0; q < 3; q++) um[q] = zero;
#pragma unroll
      for (int kt = 0; kt < 8; kt++){
        int kb = (kt * 64 + kgrp * 16) ^ msk;
        bf16x8 ah = as_bf(*(const short8*)(hhp + kb));
#pragma unroll
        for (int q = 0; q < 3; q++){
          bf16x8 bw = as_bf(*(const short8*)(wvl + ((q * 8 + kt) * 64 + lane) * 8));
          um[q] = MFMA_BF16(ah, bw, um[q], 0, 0, 0);
        }
      }
      f32x4 sp;
#pragma unroll
      for (int i = 0; i < 4; i++){
        float v = 0.f;
#pragma unroll
        for (int q = 0; q < 3; q++)
          v += wuv[q] * tanh_(um[q][i] + bvv[q]);
        sp[i] = v;
      }
#pragma unroll
      for (int d = 1; d < 16; d <<= 1){
#pragma unroll
        for (int i = 0; i < 4; i++)
          sp[i] += __shfl_xor(sp[i], d);
      }
      if (arow == 0){
#pragma unroll
        for (int i = 0; i < 4; i++){
          float e = __expf(sp[i]);
          esh[kgrp * 4 + i] = e;
          lsr[i] += e;
        }
      }
    }
    __syncthreads();   // b1 (publishes esh)

    if (t > 0){
#pragma unroll
      for (int i = 0; i < 4; i++){
        float e = esh[kgrp * 4 + i];
#pragma unroll
        for (int j = 0; j < 2; j++)
          ctxa[j][i] += e * hreg[j][i];
      }
    }

#pragma unroll
    for (int j = 0; j < 2; j++)
#pragma unroll
    for (int i = 0; i < 4; i++){
      float rr = sigm(gvr[j][i] + acc[j][i]);
      float zz = sigm(gvz[j][i] + acc[2 + j][i]);
      float nn = tanh_(gvn[j][i] + rr * (acc[4 + j][i] + bhn[j]));
      float hv = (1.0f - zz) * nn + zz * hreg[j][i];
      hreg[j][i] = hv;
      int row = kgrp * 4 + i, c = c0 + j * 128;
      short h_, l_; cvt_hilo(hv, h_, l_);
      int off = row * 512 + ((c * 2) ^ ((row & 7) << 4));
      *(short*)((char*)hhi + off) = h_;
      *(short*)((char*)hlo + off) = l_;
    }
    __syncthreads();   // b2
  }

  // epilogue: last row's scores + ctx
  if (w == 0){
    f32x4 um[3];
#pragma unroll
    for (int q = 0; q < 3; q++) um[q] = zero;
#pragma unroll
    for (int kt = 0; kt < 8; kt++){
      int kb = (kt * 64 + kgrp * 16) ^ msk;
      bf16x8 ah = as_bf(*(const short8*)(hhp + kb));
#pragma unroll
      for (int q = 0; q < 3; q++){
        bf16x8 bw = as_bf(*(const short8*)(wvl + ((q * 8 + kt) * 64 + lane) * 8));
        um[q] = MFMA_BF16(ah, bw, um[q], 0, 0, 0);
      }
    }
    f32x4 sp;
#pragma unroll
    for (int i = 0; i < 4; i++){
      float v = 0.f;
#pragma unroll
      for (int q = 0; q < 3; q++)
        v += wuv[q] * tanh_(um[q][i] + bvv[q]);
      sp[i] = v;
    }
#pragma unroll
    for (int d = 1; d < 16; d <<= 1){
#pragma unroll
      for (int i = 0; i < 4; i++)
        sp[i] += __shfl_xor(sp[i], d);
    }
    if (arow == 0){
#pragma unroll
      for (int i = 0; i < 4; i++){
        float e = __expf(sp[i]);
        esh[kgrp * 4 + i] = e;
        lsr[i] += e;
      }
    }
  }
  __syncthreads();
#pragma unroll
  for (int i = 0; i < 4; i++){
    float e = esh[kgrp * 4 + i];
#pragma unroll
    for (int j = 0; j < 2; j++)
      ctxa[j][i] += e * hreg[j][i];
  }

#pragma unroll
  for (int j = 0; j < 2; j++)
#pragma unroll
  for (int i = 0; i < 4; i++){
    int row = kgrp * 4 + i;
    hs[(size_t)(b0 + row) * H_SZ + c0 + j * 128] = hreg[j][i];
    ctx[(size_t)(b0 + row) * H_SZ + c0 + j * 128] += ctxa[j][i];
  }
  if (w == 0 && arow == 0){
#pragma unroll
    for (int i = 0; i < 4; i++)
      lsum[b0 + kgrp * 4 + i] += lsr[i];
  }
}

// ---------- fused 3-stage pipeline: inter(k-2) | leaf32(k) | gemm(k-1) ----------
__global__ __launch_bounds__(512, 2) void fused3(
    int nIb, int nLb,
    // inter (chunk k-2)
    const short* __restrict__ giI, const short* __restrict__ WhhI_,
    const float* __restrict__ bhhI_, const short* __restrict__ WvT,
    const float* __restrict__ bv, const float* __restrict__ wu,
    float* __restrict__ ctx, float* __restrict__ lsum,
    float* __restrict__ hsI, int tcntI,
    // leaf (chunk k)
    const float* __restrict__ x0, const short* __restrict__ WihL0,
    const short* __restrict__ WhhL0, const float* __restrict__ bihL0,
    const float* __restrict__ bhhL0,
    const float* __restrict__ x1, const short* __restrict__ WihL1,
    const short* __restrict__ WhhL1, const float* __restrict__ bihL1,
    const float* __restrict__ bhhL1,
    short* __restrict__ outL, float* __restrict__ hsC, float* __restrict__ hsA,
    int t0L, int tcntL,
    // gemm (chunk k-1)
    const short* __restrict__ Ag, const short* __restrict__ BhiG,
    const float* __restrict__ b1G, const float* __restrict__ b2G,
    short* __restrict__ Cg)
{
  __shared__ short smem[64 * 520];   // 66.56 KB
  int bid = blockIdx.x;
  if (bid < nIb){
    // hhi 4096 | hlo 4096 | wvl 12288 | esh
    inter_body(bid, giI, WhhI_, bhhI_, WvT, bv, wu, ctx, lsum, hsI, tcntI,
               smem, smem + 4096, smem + 8192, (float*)(smem + 20480));
  } else if (bid < nIb + nLb){
    int lb = bid - nIb;
    short* hhi = smem;                 // 32*256 = 8192 shorts
    short* hlo = smem + 8192;
    short* xhi = smem + 16384;         // 32*136 = 4352 shorts
    if (lb < 64)
      leaf32_body<128, 4>(x0, WihL0, WhhL0, bihL0, bhhL0, outL, 0, hsC,
                          lb * 32, t0L, tcntL, hhi, hlo, xhi);
    else
      leaf32_body<96, 3>(x1, WihL1, WhhL1, bihL1, bhhL1, outL, 256, hsA,
                         (lb - 64) * 32, t0L, tcntL, hhi, hlo, xhi);
  } else {
    gemm_body(bid - nIb - nLb, Ag, BhiG, b1G, b2G, Cg, smem);
  }
}

__global__ __launch_bounds__(256, 1) void attn_fin(
    const float* __restrict__ ctx, const float* __restrict__ lsum,
    float* __restrict__ out)
{
  int b = blockIdx.x, tid = threadIdx.x;
  out[(size_t)b * H_SZ + tid] = ctx[(size_t)b * H_SZ + tid] / lsum[b];
}

// ---------- host ----------
extern "C" void kernel_launch(void* const* d_in, const int* in_sizes, int n_in,
                              void* d_out, int out_size, void* d_ws, size_t ws_size,
                              hipStream_t stream)
{
  (void)in_sizes; (void)n_in; (void)out_size;
  const float* crime = (const float*)d_in[0];
  const float* anom  = (const float*)d_in[1];
  const float* WihC = (const float*)d_in[2];
  const float* WhhC = (const float*)d_in[3];
  const float* bihC = (const float*)d_in[4];
  const float* bhhC = (const float*)d_in[5];
  const float* WihA = (const float*)d_in[6];
  const float* WhhA = (const float*)d_in[7];
  const float* bihA = (const float*)d_in[8];
  const float* bhhA = (const float*)d_in[9];
  const float* WihI = (const float*)d_in[10];
  const float* WhhI = (const float*)d_in[11];
  const float* bihI = (const float*)d_in[12];
  const float* bhhI = (const float*)d_in[13];
  const float* Wv = (const float*)d_in[14];
  const float* bv = (const float*)d_in[15];
  const float* wu = (const float*)d_in[16];
  float* out = (float*)d_out;

  char* ws = (char*)d_ws;
  size_t off = 0;
  auto take = [&](size_t n){ size_t r = off; off += (n + 255) & ~(size_t)255; return r; };

  short* pIhC = (short*)(ws + take((size_t)G3 * 128 * 2));
  short* pHhC = (short*)(ws + take((size_t)G3 * 256 * 2));
  short* pIhA = (short*)(ws + take((size_t)G3 * 96 * 2));
  short* pHhA = (short*)(ws + take((size_t)G3 * 256 * 2));
  short* pIhI = (short*)(ws + take((size_t)G3 * 512 * 2));
  short* pHhI = (short*)(ws + take((size_t)G3 * 256 * 2));
  short* pWvT = (short*)(ws + take((size_t)3 * 8 * 64 * 8 * 2));

  size_t state_off = off;
  float* hsC  = (float*)(ws + take((size_t)B_SZ * H_SZ * 4));
  float* hsA  = (float*)(ws + take((size_t)B_SZ * H_SZ * 4));
  float* hsI  = (float*)(ws + take((size_t)B_SZ * H_SZ * 4));
  float* ctx  = (float*)(ws + take((size_t)B_SZ * H_SZ * 4));
  float* lsum = (float*)(ws + take((size_t)B_SZ * 4));
  size_t state_end = off;

  // double-buffered chunk scratch: 2x (Gi bf16 768 + OcaH bf16 512) per step
  size_t per2 = (size_t)B_SZ * (G3 * 2 + 512 * 2) * 2;   // 10.49 MB per timestep
  size_t avail = (ws_size > off + 8192) ? (ws_size - off - 8192) : 0;
  int TC = (int)(avail / per2);
  if (TC > 12) TC = 12;
  if (TC < 1) TC = 1;
  if (TC > T_SZ) TC = T_SZ;
  int nc = (T_SZ + TC - 1) / TC;

  short* Gi[2];  short* OcaH[2];
  Gi[0]   = (short*)(ws + take((size_t)B_SZ * TC * G3 * 2));
  Gi[1]   = (short*)(ws + take((size_t)B_SZ * TC * G3 * 2));
  OcaH[0] = (short*)(ws + take((size_t)B_SZ * TC * 512 * 2));
  OcaH[1] = (short*)(ws + take((size_t)B_SZ * TC * 512 * 2));

  auto tcn = [&](int j){
    if (j < 0 || j >= nc) return 0;
    int r = T_SZ - j * TC;
    return r < TC ? r : TC;
  };

  // zero h-states, ctx, lsum (every launch: deterministic)
  zinit<<<2048, 256, 0, stream>>>((float*)(ws + state_off), (state_end - state_off) / 4);
  packall<<<2280, 64, 0, stream>>>(WihC, WhhC, WihA, WhhA, WihI, WhhI, Wv,
                                   pIhC, pHhC, pIhA, pHhA, pIhI, pHhI, pWvT);

  // 3-stage software pipeline over chunks: inter | leaf32 | gemm per launch
  for (int k = 0; k <= nc + 1; k++){
    int tL = tcn(k), tG = tcn(k - 1), tI = tcn(k - 2);
    int nLb = tL ? 128 : 0;
    int nGb = tG ? (B_SZ * tG) / 64 : 0;
    int nIb = tI ? 128 : 0;
    int grid = nIb + nLb + nGb;
    if (grid == 0) continue;
    fused3<<<grid, 512, 0, stream>>>(
        nIb, nLb,
        Gi[k & 1], pHhI, bhhI, pWvT, bv, wu, ctx, lsum, hsI, tI,
        crime, pIhC, pHhC, bihC, bhhC,
        anom,  pIhA, pHhA, bihA, bhhA,
        OcaH[k & 1], hsC, hsA, k * TC, tL,
        OcaH[(k - 1) & 1], pIhI, bihI, bhhI, Gi[(k - 1) & 1]);
  }
  attn_fin<<<B_SZ, 256, 0, stream>>>(ctx, lsum, out);
}